// Round 3
// baseline (365.230 us; speedup 1.0000x reference)
//
#include <hip/hip_runtime.h>
#include <hip/hip_fp16.h>
#include <math.h>

namespace {

constexpr int NN = 100000;   // nodes
constexpr int NE = 1000000;  // edges
constexpr int D  = 64;       // feature dim

constexpr int RPB_LOG = 8;                        // rows per bucket = 256
constexpr int RPB = 1 << RPB_LOG;
constexpr int NBUK = (NN + RPB - 1) >> RPB_LOG;   // 391 buckets
constexpr int CAP = 4096;                         // bucket capacity (mean 2558, +30 sigma)
constexpr int TILE = 2048;                        // edges per bin tile
constexpr int NTILES = (NE + TILE - 1) / TILE;    // 489

using ushort_t = unsigned short;
typedef __attribute__((ext_vector_type(8))) short short8;  // 8 bf16 (4 VGPRs)
typedef __attribute__((ext_vector_type(4))) float f32x4;   // MFMA 16x16 accumulator

union FragU { uint4 v; short8 s; };

// split two fp32 into packed bf16 hi parts and packed bf16 lo (residual) parts.
__device__ inline void split2(float f0, float f1, unsigned int& hi, unsigned int& lo) {
    unsigned int u0 = __float_as_uint(f0);
    unsigned int u1 = __float_as_uint(f1);
    hi = (u0 >> 16) | (u1 & 0xffff0000u);
    float l0 = f0 - __uint_as_float(u0 & 0xffff0000u);
    float l1 = f1 - __uint_as_float(u1 & 0xffff0000u);
    lo = (__float_as_uint(l0) >> 16) | (__float_as_uint(l1) & 0xffff0000u);
}

__device__ inline unsigned int packh(float a, float b) {   // 2x fp16 (RNE) packed
    union { __half2 h; unsigned int u; } cv;
    cv.h = __float22half2_rn(make_float2(a, b));
    return cv.u;
}

__device__ inline float2 h2f(unsigned int v) {
    union { unsigned int u; __half2 h; } cv;
    cv.u = v;
    return __half22float2(cv.h);
}

__global__ void iperm_k(const int* __restrict__ perm, int* __restrict__ iperm, int n) {
    int i = blockIdx.x * blockDim.x + threadIdx.x;
    if (i < n) {
        iperm[perm[i]] = i;
    }
}

// Precompute A-operand fragments (A = W^T, M = out-feature) for the MFMA GEMM.
// Layout per weight matrix: [ftile(4)][ktile(2)][hi/lo(2)][lane(64)] x 16B.
// Lane l holds A[m][k] with m = ft*16 + (l&15), k = kt*32 + (l>>4)*8 + j.
__global__ void wfrag_k(const float* __restrict__ W1, const float* __restrict__ W2,
                        uint4* __restrict__ fb) {
    int lane = threadIdx.x;
    for (int w = 0; w < 2; ++w) {
        const float* W = (w != 0) ? W2 : W1;
        uint4* out = fb + w * 1024;
        for (int ft = 0; ft < 4; ++ft) {
            for (int kt = 0; kt < 2; ++kt) {
                int m  = ft * 16 + (lane & 15);
                int k0 = kt * 32 + (lane >> 4) * 8;
                unsigned int hi0, lo0, hi1, lo1, hi2, lo2, hi3, lo3;
                split2(W[(k0 + 0) * 64 + m], W[(k0 + 1) * 64 + m], hi0, lo0);
                split2(W[(k0 + 2) * 64 + m], W[(k0 + 3) * 64 + m], hi1, lo1);
                split2(W[(k0 + 4) * 64 + m], W[(k0 + 5) * 64 + m], hi2, lo2);
                split2(W[(k0 + 6) * 64 + m], W[(k0 + 7) * 64 + m], hi3, lo3);
                out[((ft * 2 + kt) * 2 + 0) * 64 + lane] = make_uint4(hi0, hi1, hi2, hi3);
                out[((ft * 2 + kt) * 2 + 1) * 64 + lane] = make_uint4(lo0, lo1, lo2, lo3);
            }
        }
    }
}

// Phase A: bin edges into 391 fixed-capacity row-range buckets.
// Payload packed: (r & 255) << 17 | c   (c < 2^17)
__global__ void bin_k(const int* __restrict__ rows, const int* __restrict__ cols,
                      int* __restrict__ bcount, unsigned int* __restrict__ binned, int e) {
    __shared__ int hist[NBUK];
    __shared__ int gbase[NBUK];
    __shared__ int lofs[NBUK];
    int base = blockIdx.x * TILE;
    for (int i = threadIdx.x; i < NBUK; i += blockDim.x) {
        hist[i] = 0;
        lofs[i] = 0;
    }
    __syncthreads();
    int r[8];
    int c[8];
    int bk[8];
#pragma unroll
    for (int j = 0; j < 8; ++j) {
        int i = base + j * 256 + threadIdx.x;
        if (i < e) {
            r[j] = rows[i];
            c[j] = cols[i];
            bk[j] = r[j] >> RPB_LOG;
            atomicAdd(&hist[bk[j]], 1);
        } else {
            bk[j] = -1;
        }
    }
    __syncthreads();
    for (int b = threadIdx.x; b < NBUK; b += blockDim.x) {
        int h = hist[b];
        gbase[b] = h ? atomicAdd(&bcount[b], h) : 0;
    }
    __syncthreads();
#pragma unroll
    for (int j = 0; j < 8; ++j) {
        if (bk[j] >= 0) {
            int l = gbase[bk[j]] + atomicAdd(&lofs[bk[j]], 1);
            if (l < CAP) {
                unsigned int v = ((unsigned int)(r[j] & (RPB - 1)) << 17) | (unsigned int)c[j];
                binned[(size_t)bk[j] * CAP + l] = v;
            }
        }
    }
}

// exclusive scan of the 391 bucket counts -> bucket bases in scols (512-thread scan)
__global__ void bucket_base_k(const int* __restrict__ bcount, int* __restrict__ bbase) {
    __shared__ int sm[512];
    int t = threadIdx.x;
    int v = (t < NBUK) ? bcount[t] : 0;
    sm[t] = v;
    __syncthreads();
    for (int off = 1; off < 512; off <<= 1) {
        int u = (t >= off) ? sm[t - off] : 0;
        __syncthreads();
        sm[t] += u;
        __syncthreads();
    }
    if (t < NBUK) {
        bbase[t] = sm[t] - v;  // exclusive
    }
}

// Phase B: per-bucket counting sort + per-row deg/rowstart/dis production.
// 391 blocks x 512 threads (was 98 x 1024 -> chip was >60% idle here).
__global__ void bucket_sort_k(const unsigned int* __restrict__ binned,
                              const int* __restrict__ bcount, const int* __restrict__ bbase,
                              int* __restrict__ scols, int* __restrict__ rowstart,
                              int* __restrict__ deg, float* __restrict__ dis) {
    __shared__ int lcur[RPB];
    __shared__ int srs[RPB];
    __shared__ int wsum[8];
    int b = blockIdx.x;
    int row0 = b << RPB_LOG;
    int nrows = min(RPB, NN - row0);
    int cnt = bcount[b];
    const unsigned int* src = binned + (size_t)b * CAP;
    int tid = threadIdx.x;
    if (tid < RPB) {
        lcur[tid] = 0;
    }
    __syncthreads();
    for (int i = tid; i < cnt; i += blockDim.x) {
        atomicAdd(&lcur[src[i] >> 17], 1);
    }
    __syncthreads();
    int d = (tid < nrows) ? lcur[tid] : 0;
    int lane = tid & 63;
    int wid = tid >> 6;
    int inc = d;
#pragma unroll
    for (int off = 1; off < 64; off <<= 1) {
        int t = __shfl_up(inc, off);
        if (lane >= off) inc += t;
    }
    if (lane == 63) wsum[wid] = inc;
    __syncthreads();
    int wpre = 0;
    for (int w = 0; w < wid; ++w) wpre += wsum[w];
    int gstart = bbase[b] + wpre + inc - d;   // global exclusive prefix
    if (tid < nrows) {
        rowstart[row0 + tid] = gstart;
        deg[row0 + tid] = d;
        dis[row0 + tid] = rsqrtf((float)(d + 1));  // +1 self-loop
    }
    __syncthreads();
    if (tid < RPB) {
        srs[tid] = gstart;
        lcur[tid] = 0;
    }
    __syncthreads();
    for (int i = tid; i < cnt; i += blockDim.x) {
        unsigned int v = src[i];
        int rl = (int)(v >> 17);
        int pos = srs[rl] + atomicAdd(&lcur[rl], 1);
        scols[pos] = (int)(v & 0x1FFFFu);
    }
}

// MFMA GEMM: D = W^T · X^T via mfma_f32_16x16x32_bf16 with bf16 hi/lo split
// (hi*hi + hi*lo + lo*hi => ~fp32 accuracy). One wave per 16-node tile.
__global__ void gemm64_mfma_k(const float* __restrict__ in, const uint4* __restrict__ wf,
                              ushort_t* __restrict__ tPN, const int* __restrict__ iperm,
                              const float* __restrict__ dis, int n, int nmod, int mode) {
    int lane  = threadIdx.x & 63;
    int wtile = (int)((blockIdx.x * blockDim.x + threadIdx.x) >> 6);
    if (wtile * 16 >= n) return;
    int node = wtile * 16 + (lane & 15);
    int kg   = lane >> 4;  // 0..3

    FragU whi[4][2];
    FragU wlo[4][2];
#pragma unroll
    for (int ft = 0; ft < 4; ++ft) {
#pragma unroll
        for (int kt = 0; kt < 2; ++kt) {
            whi[ft][kt].v = wf[((ft * 2 + kt) * 2 + 0) * 64 + lane];
            wlo[ft][kt].v = wf[((ft * 2 + kt) * 2 + 1) * 64 + lane];
        }
    }

    const float4* xr = (const float4*)in;
    size_t rbase = (size_t)node * 16 + (size_t)(kg * 2);
    f32x4 acc[4];
#pragma unroll
    for (int ft = 0; ft < 4; ++ft) {
        acc[ft] = f32x4{0.f, 0.f, 0.f, 0.f};
    }

#pragma unroll
    for (int kt = 0; kt < 2; ++kt) {
        float4 a0 = xr[rbase + kt * 8];
        float4 a1 = xr[rbase + kt * 8 + 1];
        unsigned int h0, l0, h1, l1, h2, l2, h3, l3;
        split2(a0.x, a0.y, h0, l0);
        split2(a0.z, a0.w, h1, l1);
        split2(a1.x, a1.y, h2, l2);
        split2(a1.z, a1.w, h3, l3);
        FragU xhi;
        FragU xlo;
        xhi.v = make_uint4(h0, h1, h2, h3);
        xlo.v = make_uint4(l0, l1, l2, l3);
#pragma unroll
        for (int ft = 0; ft < 4; ++ft) {
            acc[ft] = __builtin_amdgcn_mfma_f32_16x16x32_bf16(whi[ft][kt].s, xhi.s, acc[ft], 0, 0, 0);
            acc[ft] = __builtin_amdgcn_mfma_f32_16x16x32_bf16(whi[ft][kt].s, xlo.s, acc[ft], 0, 0, 0);
            acc[ft] = __builtin_amdgcn_mfma_f32_16x16x32_bf16(wlo[ft][kt].s, xhi.s, acc[ft], 0, 0, 0);
        }
    }

    int fo = kg * 4;  // feature offset inside ftile (4 consecutive feats per lane)
    if (mode == 1) {
        float sP = dis[node];
        int q = iperm[node];
        float sN = dis[q];
        ushort_t* pP = tPN + (size_t)node * 128;
        ushort_t* pN = tPN + (size_t)q * 128 + 64;
#pragma unroll
        for (int ft = 0; ft < 4; ++ft) {
            uint2 up = make_uint2(packh(sP * acc[ft][0], sP * acc[ft][1]),
                                  packh(sP * acc[ft][2], sP * acc[ft][3]));
            *(uint2*)(pP + ft * 16 + fo) = up;
            uint2 un = make_uint2(packh(sN * acc[ft][0], sN * acc[ft][1]),
                                  packh(sN * acc[ft][2], sN * acc[ft][3]));
            *(uint2*)(pN + ft * 16 + fo) = un;
        }
    } else {
        int rm  = (node >= nmod) ? node - nmod : node;
        int off = (node >= nmod) ? 64 : 0;
        float s = dis[rm];
        ushort_t* p = tPN + (size_t)rm * 128 + off;
#pragma unroll
        for (int ft = 0; ft < 4; ++ft) {
            uint2 u = make_uint2(packh(s * acc[ft][0], s * acc[ft][1]),
                                 packh(s * acc[ft][2], s * acc[ft][3]));
            *(uint2*)(p + ft * 16 + fo) = u;
        }
    }
}

// Dual gather-aggregate, MLP-restructured. One wave per row.
// 8B loads: 32 lanes cover one neighbor's full 256B row (16 lanes P-half,
// 16 lanes N-half, 4 fp16 features each); lanes 32-63 process the NEXT
// neighbor. Unroll 4 -> 8 neighbor-slots in flight, tail via predication.
// Self-loop is virtual slot k == dg. Cross-half merge: 4x shfl_xor(32).
__global__ void agg_dual_k(const ushort_t* __restrict__ tPN,
                           float* __restrict__ dstP, float* __restrict__ dstN,
                           const float* __restrict__ dis,
                           const int* __restrict__ rowstart, const int* __restrict__ deg,
                           const int* __restrict__ scols,
                           const float* __restrict__ bias, const float* __restrict__ prelu_a,
                           int n) {
    int lane = threadIdx.x & 63;
    int r = blockIdx.x * (blockDim.x >> 6) + (threadIdx.x >> 6);
    if (r >= n) return;
    int rs   = __builtin_amdgcn_readfirstlane(r);
    int base = __builtin_amdgcn_readfirstlane(rowstart[rs]);
    int dg   = __builtin_amdgcn_readfirstlane(deg[rs]);
    int m    = dg + 1;                 // + virtual self slot
    int pair = lane >> 5;              // which slot parity this lane covers
    int sub  = lane & 31;
    int half = sub >> 4;               // 0 = P, 1 = N
    int q    = sub & 15;               // feature quad index
    const char* tb = (const char*)tPN;
    size_t lofs = (size_t)half * 128 + (size_t)q * 8;
    float a0 = 0.f;
    float a1 = 0.f;
    float a2 = 0.f;
    float a3 = 0.f;
    for (int j0 = 0; j0 < m; j0 += 8) {
#pragma unroll
        for (int u = 0; u < 4; ++u) {
            int k = j0 + 2 * u + pair;
            if (k < m) {
                int c = (k < dg) ? scols[base + k] : rs;
                uint2 v = *(const uint2*)(tb + (size_t)c * 256 + lofs);
                float2 p0 = h2f(v.x);
                float2 p1 = h2f(v.y);
                a0 += p0.x;
                a1 += p0.y;
                a2 += p1.x;
                a3 += p1.y;
            }
        }
    }
    a0 += __shfl_xor(a0, 32, 64);
    a1 += __shfl_xor(a1, 32, 64);
    a2 += __shfl_xor(a2, 32, 64);
    a3 += __shfl_xor(a3, 32, 64);
    if (pair == 0) {
        float dr = dis[rs];
        float4 bv = *(const float4*)(bias + 4 * q);
        float v0 = fmaf(dr, a0, bv.x);
        float v1 = fmaf(dr, a1, bv.y);
        float v2 = fmaf(dr, a2, bv.z);
        float v3 = fmaf(dr, a3, bv.w);
        if (prelu_a) {
            float a = *prelu_a;
            v0 = v0 >= 0.f ? v0 : a * v0;
            v1 = v1 >= 0.f ? v1 : a * v1;
            v2 = v2 >= 0.f ? v2 : a * v2;
            v3 = v3 >= 0.f ? v3 : a * v3;
        }
        float* dst = half ? dstN : dstP;
        *(float4*)(dst + (size_t)rs * D + 4 * q) = float4{v0, v1, v2, v3};
    }
}

__global__ void summary_partial_k(const float* __restrict__ pos, float* __restrict__ acc, int n) {
    int lane = threadIdx.x & 63;
    int wave = (blockIdx.x * blockDim.x + threadIdx.x) >> 6;
    int nw = (gridDim.x * blockDim.x) >> 6;
    float s = 0.f;
    for (int r = wave; r < n; r += nw) {
        s += pos[(size_t)r * D + lane];
    }
    atomicAdd(&acc[lane], s);
}

__global__ void summary_final_k(const float* __restrict__ acc, float* __restrict__ out, int n) {
    int f = threadIdx.x;
    if (f < D) {
        float m = acc[f] / (float)n;
        out[f] = 1.f / (1.f + expf(-m));
    }
}

} // namespace

extern "C" void kernel_launch(void* const* d_in, const int* in_sizes, int n_in,
                              void* d_out, int out_size, void* d_ws, size_t ws_size,
                              hipStream_t stream) {
    (void)in_sizes; (void)n_in; (void)out_size; (void)ws_size;
    const float* x       = (const float*)d_in[0];
    const int*   ei      = (const int*)  d_in[1];
    const int*   perm    = (const int*)  d_in[2];
    const float* W1      = (const float*)d_in[3];
    const float* b1      = (const float*)d_in[4];
    const float* prelu_a = (const float*)d_in[5];
    const float* W2      = (const float*)d_in[6];
    const float* b2      = (const float*)d_in[7];

    float* outP = (float*)d_out;
    float* outN = outP + (size_t)NN * D;
    float* outS = outN + (size_t)NN * D;

    const int* erows = ei;
    const int* ecols = ei + NE;

    char* ws = (char*)d_ws;
    size_t off = 0;
    auto alloc = [&](size_t bytes) {
        void* p = ws + off;
        off = (off + bytes + 255) & ~(size_t)255;
        return p;
    };
    int*      deg      = (int*)     alloc((size_t)NN * 4);
    float*    dis      = (float*)   alloc((size_t)NN * 4);
    int*      rowstart = (int*)     alloc((size_t)NN * 4);
    int*      iperm    = (int*)     alloc((size_t)NN * 4);
    int*      bcount   = (int*)     alloc((size_t)NBUK * 4);
    int*      bbase    = (int*)     alloc((size_t)NBUK * 4);
    unsigned int* binned = (unsigned int*)alloc((size_t)NBUK * CAP * 4);  // 6.4 MB
    int*      scols    = (int*)     alloc((size_t)NE * 4);
    ushort_t* tPN      = (ushort_t*)alloc((size_t)NN * 128 * 2);   // interleaved dual table (fp16), 25.6 MB
    float*    aggPN    = (float*)   alloc((size_t)2 * NN * D * 4); // [aggP | aggN], 51.2 MB
    float*    aggP     = aggPN;
    float*    aggN     = aggPN + (size_t)NN * D;
    float*    acc      = (float*)   alloc((size_t)D * 4);
    uint4*    wfrag    = (uint4*)   alloc((size_t)2 * 1024 * 16);  // W1|W2 bf16 hi/lo frags, 32 KB
    // ~90 MB total

    hipMemsetAsync(bcount, 0, (size_t)NBUK * 4, stream);
    hipMemsetAsync(acc, 0, (size_t)D * 4, stream);

    // graph preprocessing: bin -> base scan -> per-bucket sort (+deg/rowstart/dis)
    iperm_k<<<(NN + 255) / 256, 256, 0, stream>>>(perm, iperm, NN);
    wfrag_k<<<1, 64, 0, stream>>>(W1, W2, wfrag);
    bin_k<<<NTILES, 256, 0, stream>>>(erows, ecols, bcount, binned, NE);
    bucket_base_k<<<1, 512, 0, stream>>>(bcount, bbase);
    bucket_sort_k<<<NBUK, 512, 0, stream>>>(binned, bcount, bbase, scols, rowstart, deg, dis);

    const int aggBlocks = (NN + 3) / 4;

    // layer 1: tPN[c] = [dis[c]*xw[c] | dis[c]*xw[perm[c]]]  (one MFMA gemm, fused scatter)
    gemm64_mfma_k<<<(NN / 16 + 3) / 4, 256, 0, stream>>>(x, wfrag, tPN, iperm, dis, NN, NN, 1);
    agg_dual_k<<<aggBlocks, 256, 0, stream>>>(tPN, aggP, aggN, dis, rowstart, deg,
                                              scols, b1, prelu_a, NN);

    // layer 2: one MFMA gemm over [aggP|aggN] (200k rows) -> interleaved scaled table
    gemm64_mfma_k<<<(2 * NN / 16 + 3) / 4, 256, 0, stream>>>(aggPN, wfrag + 1024, tPN, nullptr,
                                                             dis, 2 * NN, NN, 2);
    agg_dual_k<<<aggBlocks, 256, 0, stream>>>(tPN, outP, outN, dis, rowstart, deg,
                                              scols, b2, nullptr, NN);

    // summary = sigmoid(mean(positive, axis=0))
    summary_partial_k<<<256, 256, 0, stream>>>(outP, acc, NN);
    summary_final_k<<<1, 64, 0, stream>>>(acc, outS, NN);
}

// Round 4
// 317.451 us; speedup vs baseline: 1.1505x; 1.1505x over previous
//
#include <hip/hip_runtime.h>
#include <hip/hip_fp16.h>
#include <math.h>

namespace {

constexpr int NN = 100000;   // nodes
constexpr int NE = 1000000;  // edges
constexpr int D  = 64;       // feature dim

constexpr int RPB_LOG = 8;                        // rows per bucket = 256
constexpr int RPB = 1 << RPB_LOG;
constexpr int NBUK = (NN + RPB - 1) >> RPB_LOG;   // 391 buckets
constexpr int CAP = 4096;                         // bucket capacity (mean 2558, +30 sigma)
constexpr int TILE = 2048;                        // edges per bin tile
constexpr int NTILES = (NE + TILE - 1) / TILE;    // 489

using ushort_t = unsigned short;
typedef __attribute__((ext_vector_type(8))) short short8;  // 8 bf16 (4 VGPRs)
typedef __attribute__((ext_vector_type(4))) float f32x4;   // MFMA 16x16 accumulator

union FragU { uint4 v; short8 s; };

// split two fp32 into packed bf16 hi parts and packed bf16 lo (residual) parts.
__device__ inline void split2(float f0, float f1, unsigned int& hi, unsigned int& lo) {
    unsigned int u0 = __float_as_uint(f0);
    unsigned int u1 = __float_as_uint(f1);
    hi = (u0 >> 16) | (u1 & 0xffff0000u);
    float l0 = f0 - __uint_as_float(u0 & 0xffff0000u);
    float l1 = f1 - __uint_as_float(u1 & 0xffff0000u);
    lo = (__float_as_uint(l0) >> 16) | (__float_as_uint(l1) & 0xffff0000u);
}

__device__ inline unsigned int packh(float a, float b) {   // 2x fp16 (RNE) packed
    union { __half2 h; unsigned int u; } cv;
    cv.h = __float22half2_rn(make_float2(a, b));
    return cv.u;
}

__device__ inline float2 h2f(unsigned int v) {
    union { unsigned int u; __half2 h; } cv;
    cv.u = v;
    return __half22float2(cv.h);
}

__global__ void iperm_k(const int* __restrict__ perm, int* __restrict__ iperm, int n) {
    int i = blockIdx.x * blockDim.x + threadIdx.x;
    if (i < n) {
        iperm[perm[i]] = i;
    }
}

// Precompute A-operand fragments (A = W^T, M = out-feature) for the MFMA GEMM.
// Layout per weight matrix: [ftile(4)][ktile(2)][hi/lo(2)][lane(64)] x 16B.
// Lane l holds A[m][k] with m = ft*16 + (l&15), k = kt*32 + (l>>4)*8 + j.
__global__ void wfrag_k(const float* __restrict__ W1, const float* __restrict__ W2,
                        uint4* __restrict__ fb) {
    int lane = threadIdx.x;
    for (int w = 0; w < 2; ++w) {
        const float* W = (w != 0) ? W2 : W1;
        uint4* out = fb + w * 1024;
        for (int ft = 0; ft < 4; ++ft) {
            for (int kt = 0; kt < 2; ++kt) {
                int m  = ft * 16 + (lane & 15);
                int k0 = kt * 32 + (lane >> 4) * 8;
                unsigned int hi0, lo0, hi1, lo1, hi2, lo2, hi3, lo3;
                split2(W[(k0 + 0) * 64 + m], W[(k0 + 1) * 64 + m], hi0, lo0);
                split2(W[(k0 + 2) * 64 + m], W[(k0 + 3) * 64 + m], hi1, lo1);
                split2(W[(k0 + 4) * 64 + m], W[(k0 + 5) * 64 + m], hi2, lo2);
                split2(W[(k0 + 6) * 64 + m], W[(k0 + 7) * 64 + m], hi3, lo3);
                out[((ft * 2 + kt) * 2 + 0) * 64 + lane] = make_uint4(hi0, hi1, hi2, hi3);
                out[((ft * 2 + kt) * 2 + 1) * 64 + lane] = make_uint4(lo0, lo1, lo2, lo3);
            }
        }
    }
}

// Phase A: bin edges into 391 fixed-capacity row-range buckets.
// Payload packed: (r & 255) << 17 | c   (c < 2^17)
__global__ void bin_k(const int* __restrict__ rows, const int* __restrict__ cols,
                      int* __restrict__ bcount, unsigned int* __restrict__ binned, int e) {
    __shared__ int hist[NBUK];
    __shared__ int gbase[NBUK];
    __shared__ int lofs[NBUK];
    int base = blockIdx.x * TILE;
    for (int i = threadIdx.x; i < NBUK; i += blockDim.x) {
        hist[i] = 0;
        lofs[i] = 0;
    }
    __syncthreads();
    int r[8];
    int c[8];
    int bk[8];
#pragma unroll
    for (int j = 0; j < 8; ++j) {
        int i = base + j * 256 + threadIdx.x;
        if (i < e) {
            r[j] = rows[i];
            c[j] = cols[i];
            bk[j] = r[j] >> RPB_LOG;
            atomicAdd(&hist[bk[j]], 1);
        } else {
            bk[j] = -1;
        }
    }
    __syncthreads();
    for (int b = threadIdx.x; b < NBUK; b += blockDim.x) {
        int h = hist[b];
        gbase[b] = h ? atomicAdd(&bcount[b], h) : 0;
    }
    __syncthreads();
#pragma unroll
    for (int j = 0; j < 8; ++j) {
        if (bk[j] >= 0) {
            int l = gbase[bk[j]] + atomicAdd(&lofs[bk[j]], 1);
            if (l < CAP) {
                unsigned int v = ((unsigned int)(r[j] & (RPB - 1)) << 17) | (unsigned int)c[j];
                binned[(size_t)bk[j] * CAP + l] = v;
            }
        }
    }
}

// exclusive scan of the 391 bucket counts -> bucket bases in scols (512-thread scan)
__global__ void bucket_base_k(const int* __restrict__ bcount, int* __restrict__ bbase) {
    __shared__ int sm[512];
    int t = threadIdx.x;
    int v = (t < NBUK) ? bcount[t] : 0;
    sm[t] = v;
    __syncthreads();
    for (int off = 1; off < 512; off <<= 1) {
        int u = (t >= off) ? sm[t - off] : 0;
        __syncthreads();
        sm[t] += u;
        __syncthreads();
    }
    if (t < NBUK) {
        bbase[t] = sm[t] - v;  // exclusive
    }
}

// Phase B: per-bucket counting sort + per-row deg/rowstart/dis production.
__global__ void bucket_sort_k(const unsigned int* __restrict__ binned,
                              const int* __restrict__ bcount, const int* __restrict__ bbase,
                              int* __restrict__ scols, int* __restrict__ rowstart,
                              int* __restrict__ deg, float* __restrict__ dis) {
    __shared__ int lcur[RPB];
    __shared__ int srs[RPB];
    __shared__ int wsum[8];
    int b = blockIdx.x;
    int row0 = b << RPB_LOG;
    int nrows = min(RPB, NN - row0);
    int cnt = bcount[b];
    const unsigned int* src = binned + (size_t)b * CAP;
    int tid = threadIdx.x;
    if (tid < RPB) {
        lcur[tid] = 0;
    }
    __syncthreads();
    for (int i = tid; i < cnt; i += blockDim.x) {
        atomicAdd(&lcur[src[i] >> 17], 1);
    }
    __syncthreads();
    int d = (tid < nrows) ? lcur[tid] : 0;
    int lane = tid & 63;
    int wid = tid >> 6;
    int inc = d;
#pragma unroll
    for (int off = 1; off < 64; off <<= 1) {
        int t = __shfl_up(inc, off);
        if (lane >= off) inc += t;
    }
    if (lane == 63) wsum[wid] = inc;
    __syncthreads();
    int wpre = 0;
    for (int w = 0; w < wid; ++w) wpre += wsum[w];
    int gstart = bbase[b] + wpre + inc - d;   // global exclusive prefix
    if (tid < nrows) {
        rowstart[row0 + tid] = gstart;
        deg[row0 + tid] = d;
        dis[row0 + tid] = rsqrtf((float)(d + 1));  // +1 self-loop
    }
    __syncthreads();
    if (tid < RPB) {
        srs[tid] = gstart;
        lcur[tid] = 0;
    }
    __syncthreads();
    for (int i = tid; i < cnt; i += blockDim.x) {
        unsigned int v = src[i];
        int rl = (int)(v >> 17);
        int pos = srs[rl] + atomicAdd(&lcur[rl], 1);
        scols[pos] = (int)(v & 0x1FFFFu);
    }
}

// MFMA GEMM: D = W^T · X^T via mfma_f32_16x16x32_bf16 with bf16 hi/lo split
// (hi*hi + hi*lo + lo*hi => ~fp32 accuracy). One wave per 16-node tile.
__global__ void gemm64_mfma_k(const float* __restrict__ in, const uint4* __restrict__ wf,
                              ushort_t* __restrict__ tPN, const int* __restrict__ iperm,
                              const float* __restrict__ dis, int n, int nmod, int mode) {
    int lane  = threadIdx.x & 63;
    int wtile = (int)((blockIdx.x * blockDim.x + threadIdx.x) >> 6);
    if (wtile * 16 >= n) return;
    int node = wtile * 16 + (lane & 15);
    int kg   = lane >> 4;  // 0..3

    FragU whi[4][2];
    FragU wlo[4][2];
#pragma unroll
    for (int ft = 0; ft < 4; ++ft) {
#pragma unroll
        for (int kt = 0; kt < 2; ++kt) {
            whi[ft][kt].v = wf[((ft * 2 + kt) * 2 + 0) * 64 + lane];
            wlo[ft][kt].v = wf[((ft * 2 + kt) * 2 + 1) * 64 + lane];
        }
    }

    const float4* xr = (const float4*)in;
    size_t rbase = (size_t)node * 16 + (size_t)(kg * 2);
    f32x4 acc[4];
#pragma unroll
    for (int ft = 0; ft < 4; ++ft) {
        acc[ft] = f32x4{0.f, 0.f, 0.f, 0.f};
    }

#pragma unroll
    for (int kt = 0; kt < 2; ++kt) {
        float4 a0 = xr[rbase + kt * 8];
        float4 a1 = xr[rbase + kt * 8 + 1];
        unsigned int h0, l0, h1, l1, h2, l2, h3, l3;
        split2(a0.x, a0.y, h0, l0);
        split2(a0.z, a0.w, h1, l1);
        split2(a1.x, a1.y, h2, l2);
        split2(a1.z, a1.w, h3, l3);
        FragU xhi;
        FragU xlo;
        xhi.v = make_uint4(h0, h1, h2, h3);
        xlo.v = make_uint4(l0, l1, l2, l3);
#pragma unroll
        for (int ft = 0; ft < 4; ++ft) {
            acc[ft] = __builtin_amdgcn_mfma_f32_16x16x32_bf16(whi[ft][kt].s, xhi.s, acc[ft], 0, 0, 0);
            acc[ft] = __builtin_amdgcn_mfma_f32_16x16x32_bf16(whi[ft][kt].s, xlo.s, acc[ft], 0, 0, 0);
            acc[ft] = __builtin_amdgcn_mfma_f32_16x16x32_bf16(wlo[ft][kt].s, xhi.s, acc[ft], 0, 0, 0);
        }
    }

    int fo = kg * 4;  // feature offset inside ftile (4 consecutive feats per lane)
    if (mode == 1) {
        float sP = dis[node];
        int q = iperm[node];
        float sN = dis[q];
        ushort_t* pP = tPN + (size_t)node * 128;
        ushort_t* pN = tPN + (size_t)q * 128 + 64;
#pragma unroll
        for (int ft = 0; ft < 4; ++ft) {
            uint2 up = make_uint2(packh(sP * acc[ft][0], sP * acc[ft][1]),
                                  packh(sP * acc[ft][2], sP * acc[ft][3]));
            *(uint2*)(pP + ft * 16 + fo) = up;
            uint2 un = make_uint2(packh(sN * acc[ft][0], sN * acc[ft][1]),
                                  packh(sN * acc[ft][2], sN * acc[ft][3]));
            *(uint2*)(pN + ft * 16 + fo) = un;
        }
    } else {
        int rm  = (node >= nmod) ? node - nmod : node;
        int off = (node >= nmod) ? 64 : 0;
        float s = dis[rm];
        ushort_t* p = tPN + (size_t)rm * 128 + off;
#pragma unroll
        for (int ft = 0; ft < 4; ++ft) {
            uint2 u = make_uint2(packh(s * acc[ft][0], s * acc[ft][1]),
                                 packh(s * acc[ft][2], s * acc[ft][3]));
            *(uint2*)(p + ft * 16 + fo) = u;
        }
    }
}

// Dual gather-aggregate. One wave per row. Wide-gather structure:
// each gather instruction covers FOUR neighbor rows (quad = lane>>4 selects
// among 4 SGPR-resident column ids via cndmask; sub = lane&15 reads 16B of
// the 256B row -> global_load_dwordx4, 1KB/instr). scols indices stay
// wave-uniform => scalar loads (the R3 regression was losing this).
// Hot path: unpredicated batches of 16 neighbors (4 gathers, 4KB in flight).
// Exactly one predicated tail batch handles remainder + virtual self slot
// (slot k == dg -> row rs). Cross-quad reduce: shfl_xor 16/32; lanes 0-15
// hold the full 128-feature sum (sub<8 = P features, sub>=8 = N features).
__global__ void agg_dual_k(const ushort_t* __restrict__ tPN,
                           float* __restrict__ dstP, float* __restrict__ dstN,
                           const float* __restrict__ dis,
                           const int* __restrict__ rowstart, const int* __restrict__ deg,
                           const int* __restrict__ scols,
                           const float* __restrict__ bias, const float* __restrict__ prelu_a,
                           int n) {
    int lane = threadIdx.x & 63;
    int r = blockIdx.x * (blockDim.x >> 6) + (threadIdx.x >> 6);
    if (r >= n) return;
    int rs   = __builtin_amdgcn_readfirstlane(r);
    int base = __builtin_amdgcn_readfirstlane(rowstart[rs]);
    int dg   = __builtin_amdgcn_readfirstlane(deg[rs]);
    int m    = dg + 1;                  // + virtual self-loop slot
    int quad = lane >> 4;               // which of 4 concurrent neighbor slots
    int sub  = lane & 15;               // 16B segment within the 256B row
    const char* tb = (const char*)tPN;
    size_t lofs = (size_t)sub * 16;
    float a0 = 0.f, a1 = 0.f, a2 = 0.f, a3 = 0.f;
    float a4 = 0.f, a5 = 0.f, a6 = 0.f, a7 = 0.f;

    int j0 = 0;
    // full batches: 16 real neighbors, no predication, scols loads scalar
    for (; j0 + 16 <= dg; j0 += 16) {
#pragma unroll
        for (int u = 0; u < 4; ++u) {
            int kq = j0 + 4 * u;
            int c0 = scols[base + kq];
            int c1 = scols[base + kq + 1];
            int c2 = scols[base + kq + 2];
            int c3 = scols[base + kq + 3];
            int c = (quad & 2) ? ((quad & 1) ? c3 : c2) : ((quad & 1) ? c1 : c0);
            uint4 v = *(const uint4*)(tb + (size_t)c * 256 + lofs);
            float2 p0 = h2f(v.x);
            float2 p1 = h2f(v.y);
            float2 p2 = h2f(v.z);
            float2 p3 = h2f(v.w);
            a0 += p0.x; a1 += p0.y; a2 += p1.x; a3 += p1.y;
            a4 += p2.x; a5 += p2.y; a6 += p3.x; a7 += p3.y;
        }
    }
    // single tail batch: slots j0..m-1 (m - j0 <= 16), self slot k == dg
#pragma unroll
    for (int u = 0; u < 4; ++u) {
        int kq = j0 + 4 * u;
        if (kq < m) {                       // uniform
            int c0 = (kq     < dg) ? scols[base + kq]     : rs;
            int c1 = (kq + 1 < dg) ? scols[base + kq + 1] : rs;
            int c2 = (kq + 2 < dg) ? scols[base + kq + 2] : rs;
            int c3 = (kq + 3 < dg) ? scols[base + kq + 3] : rs;
            int c = (quad & 2) ? ((quad & 1) ? c3 : c2) : ((quad & 1) ? c1 : c0);
            if (kq + quad < m) {            // per-quad mask
                uint4 v = *(const uint4*)(tb + (size_t)c * 256 + lofs);
                float2 p0 = h2f(v.x);
                float2 p1 = h2f(v.y);
                float2 p2 = h2f(v.z);
                float2 p3 = h2f(v.w);
                a0 += p0.x; a1 += p0.y; a2 += p1.x; a3 += p1.y;
                a4 += p2.x; a5 += p2.y; a6 += p3.x; a7 += p3.y;
            }
        }
    }

    // cross-quad reduction (quads hold disjoint neighbor subsets)
    a0 += __shfl_xor(a0, 16, 64); a0 += __shfl_xor(a0, 32, 64);
    a1 += __shfl_xor(a1, 16, 64); a1 += __shfl_xor(a1, 32, 64);
    a2 += __shfl_xor(a2, 16, 64); a2 += __shfl_xor(a2, 32, 64);
    a3 += __shfl_xor(a3, 16, 64); a3 += __shfl_xor(a3, 32, 64);
    a4 += __shfl_xor(a4, 16, 64); a4 += __shfl_xor(a4, 32, 64);
    a5 += __shfl_xor(a5, 16, 64); a5 += __shfl_xor(a5, 32, 64);
    a6 += __shfl_xor(a6, 16, 64); a6 += __shfl_xor(a6, 32, 64);
    a7 += __shfl_xor(a7, 16, 64); a7 += __shfl_xor(a7, 32, 64);

    if (quad == 0) {
        float dr = dis[rs];
        int hf = sub >> 3;                 // 0 = P, 1 = N
        int f0 = (sub & 7) << 3;           // feature octet base
        float4 b0 = *(const float4*)(bias + f0);
        float4 b1 = *(const float4*)(bias + f0 + 4);
        float o0 = fmaf(dr, a0, b0.x);
        float o1 = fmaf(dr, a1, b0.y);
        float o2 = fmaf(dr, a2, b0.z);
        float o3 = fmaf(dr, a3, b0.w);
        float o4 = fmaf(dr, a4, b1.x);
        float o5 = fmaf(dr, a5, b1.y);
        float o6 = fmaf(dr, a6, b1.z);
        float o7 = fmaf(dr, a7, b1.w);
        if (prelu_a) {
            float aa = *prelu_a;
            o0 = o0 >= 0.f ? o0 : aa * o0;
            o1 = o1 >= 0.f ? o1 : aa * o1;
            o2 = o2 >= 0.f ? o2 : aa * o2;
            o3 = o3 >= 0.f ? o3 : aa * o3;
            o4 = o4 >= 0.f ? o4 : aa * o4;
            o5 = o5 >= 0.f ? o5 : aa * o5;
            o6 = o6 >= 0.f ? o6 : aa * o6;
            o7 = o7 >= 0.f ? o7 : aa * o7;
        }
        float* dst = hf ? dstN : dstP;
        *(float4*)(dst + (size_t)rs * D + f0)     = float4{o0, o1, o2, o3};
        *(float4*)(dst + (size_t)rs * D + f0 + 4) = float4{o4, o5, o6, o7};
    }
}

__global__ void summary_partial_k(const float* __restrict__ pos, float* __restrict__ acc, int n) {
    int lane = threadIdx.x & 63;
    int wave = (blockIdx.x * blockDim.x + threadIdx.x) >> 6;
    int nw = (gridDim.x * blockDim.x) >> 6;
    float s = 0.f;
    for (int r = wave; r < n; r += nw) {
        s += pos[(size_t)r * D + lane];
    }
    atomicAdd(&acc[lane], s);
}

__global__ void summary_final_k(const float* __restrict__ acc, float* __restrict__ out, int n) {
    int f = threadIdx.x;
    if (f < D) {
        float m = acc[f] / (float)n;
        out[f] = 1.f / (1.f + expf(-m));
    }
}

} // namespace

extern "C" void kernel_launch(void* const* d_in, const int* in_sizes, int n_in,
                              void* d_out, int out_size, void* d_ws, size_t ws_size,
                              hipStream_t stream) {
    (void)in_sizes; (void)n_in; (void)out_size; (void)ws_size;
    const float* x       = (const float*)d_in[0];
    const int*   ei      = (const int*)  d_in[1];
    const int*   perm    = (const int*)  d_in[2];
    const float* W1      = (const float*)d_in[3];
    const float* b1      = (const float*)d_in[4];
    const float* prelu_a = (const float*)d_in[5];
    const float* W2      = (const float*)d_in[6];
    const float* b2      = (const float*)d_in[7];

    float* outP = (float*)d_out;
    float* outN = outP + (size_t)NN * D;
    float* outS = outN + (size_t)NN * D;

    const int* erows = ei;
    const int* ecols = ei + NE;

    char* ws = (char*)d_ws;
    size_t off = 0;
    auto alloc = [&](size_t bytes) {
        void* p = ws + off;
        off = (off + bytes + 255) & ~(size_t)255;
        return p;
    };
    int*      deg      = (int*)     alloc((size_t)NN * 4);
    float*    dis      = (float*)   alloc((size_t)NN * 4);
    int*      rowstart = (int*)     alloc((size_t)NN * 4);
    int*      iperm    = (int*)     alloc((size_t)NN * 4);
    int*      bcount   = (int*)     alloc((size_t)NBUK * 4);
    int*      bbase    = (int*)     alloc((size_t)NBUK * 4);
    unsigned int* binned = (unsigned int*)alloc((size_t)NBUK * CAP * 4);  // 6.4 MB
    int*      scols    = (int*)     alloc((size_t)NE * 4);
    ushort_t* tPN      = (ushort_t*)alloc((size_t)NN * 128 * 2);   // interleaved dual table (fp16), 25.6 MB
    float*    aggPN    = (float*)   alloc((size_t)2 * NN * D * 4); // [aggP | aggN], 51.2 MB
    float*    aggP     = aggPN;
    float*    aggN     = aggPN + (size_t)NN * D;
    float*    acc      = (float*)   alloc((size_t)D * 4);
    uint4*    wfrag    = (uint4*)   alloc((size_t)2 * 1024 * 16);  // W1|W2 bf16 hi/lo frags, 32 KB
    // ~90 MB total

    hipMemsetAsync(bcount, 0, (size_t)NBUK * 4, stream);
    hipMemsetAsync(acc, 0, (size_t)D * 4, stream);

    // graph preprocessing: bin -> base scan -> per-bucket sort (+deg/rowstart/dis)
    iperm_k<<<(NN + 255) / 256, 256, 0, stream>>>(perm, iperm, NN);
    wfrag_k<<<1, 64, 0, stream>>>(W1, W2, wfrag);
    bin_k<<<NTILES, 256, 0, stream>>>(erows, ecols, bcount, binned, NE);
    bucket_base_k<<<1, 512, 0, stream>>>(bcount, bbase);
    bucket_sort_k<<<NBUK, 512, 0, stream>>>(binned, bcount, bbase, scols, rowstart, deg, dis);

    const int aggBlocks = (NN + 3) / 4;

    // layer 1: tPN[c] = [dis[c]*xw[c] | dis[c]*xw[perm[c]]]  (one MFMA gemm, fused scatter)
    gemm64_mfma_k<<<(NN / 16 + 3) / 4, 256, 0, stream>>>(x, wfrag, tPN, iperm, dis, NN, NN, 1);
    agg_dual_k<<<aggBlocks, 256, 0, stream>>>(tPN, aggP, aggN, dis, rowstart, deg,
                                              scols, b1, prelu_a, NN);

    // layer 2: one MFMA gemm over [aggP|aggN] (200k rows) -> interleaved scaled table
    gemm64_mfma_k<<<(2 * NN / 16 + 3) / 4, 256, 0, stream>>>(aggPN, wfrag + 1024, tPN, nullptr,
                                                             dis, 2 * NN, NN, 2);
    agg_dual_k<<<aggBlocks, 256, 0, stream>>>(tPN, outP, outN, dis, rowstart, deg,
                                              scols, b2, nullptr, NN);

    // summary = sigmoid(mean(positive, axis=0))
    summary_partial_k<<<256, 256, 0, stream>>>(outP, acc, NN);
    summary_final_k<<<1, 64, 0, stream>>>(acc, outS, NN);
}

// Round 5
// 300.638 us; speedup vs baseline: 1.2148x; 1.0559x over previous
//
#include <hip/hip_runtime.h>
#include <hip/hip_fp16.h>
#include <math.h>

namespace {

constexpr int NN = 100000;   // nodes
constexpr int NE = 1000000;  // edges
constexpr int D  = 64;       // feature dim

constexpr int RPB_LOG = 8;                        // rows per bucket = 256
constexpr int RPB = 1 << RPB_LOG;
constexpr int NBUK = (NN + RPB - 1) >> RPB_LOG;   // 391 buckets
constexpr int CAP = 4096;                         // bucket capacity (mean 2558, +30 sigma)
constexpr int TILE = 2048;                        // edges per bin tile
constexpr int NTILES = (NE + TILE - 1) / TILE;    // 489
constexpr int SUMW = 1024;                        // summary partial waves

using ushort_t = unsigned short;
typedef __attribute__((ext_vector_type(8))) short short8;  // 8 bf16 (4 VGPRs)
typedef __attribute__((ext_vector_type(4))) float f32x4;   // MFMA 16x16 accumulator

union FragU { uint4 v; short8 s; };

// split two fp32 into packed bf16 hi parts and packed bf16 lo (residual) parts.
__device__ inline void split2(float f0, float f1, unsigned int& hi, unsigned int& lo) {
    unsigned int u0 = __float_as_uint(f0);
    unsigned int u1 = __float_as_uint(f1);
    hi = (u0 >> 16) | (u1 & 0xffff0000u);
    float l0 = f0 - __uint_as_float(u0 & 0xffff0000u);
    float l1 = f1 - __uint_as_float(u1 & 0xffff0000u);
    lo = (__float_as_uint(l0) >> 16) | (__float_as_uint(l1) & 0xffff0000u);
}

__device__ inline unsigned int packh(float a, float b) {   // 2x fp16 (RNE) packed
    union { __half2 h; unsigned int u; } cv;
    cv.h = __float22half2_rn(make_float2(a, b));
    return cv.u;
}

__device__ inline float2 h2f(unsigned int v) {
    union { unsigned int u; __half2 h; } cv;
    cv.u = v;
    return __half22float2(cv.h);
}

// Fused Phase A + weight-fragment precompute.
// Blocks [0, NTILES): bin edges into 391 fixed-capacity row-range buckets.
//   Payload packed: (r & 255) << 17 | c   (c < 2^17)
// Block NTILES: build MFMA A-operand fragments for W1|W2 (bf16 hi/lo),
//   layout per matrix: [ftile(4)][ktile(2)][hi/lo(2)][lane(64)] x 16B;
//   lane l holds A[m][k], m = ft*16 + (l&15), k = kt*32 + (l>>4)*8 + j.
__global__ void binw_k(const int* __restrict__ rows, const int* __restrict__ cols,
                       int* __restrict__ bcount, unsigned int* __restrict__ binned, int e,
                       const float* __restrict__ W1, const float* __restrict__ W2,
                       uint4* __restrict__ fb) {
    __shared__ int hist[NBUK];
    __shared__ int gbase[NBUK];
    __shared__ int lofs[NBUK];
    if (blockIdx.x == NTILES) {
        int lane = threadIdx.x;
        if (lane < 64) {
            for (int w = 0; w < 2; ++w) {
                const float* W = (w != 0) ? W2 : W1;
                uint4* out = fb + w * 1024;
                for (int ft = 0; ft < 4; ++ft) {
                    for (int kt = 0; kt < 2; ++kt) {
                        int m  = ft * 16 + (lane & 15);
                        int k0 = kt * 32 + (lane >> 4) * 8;
                        unsigned int hi0, lo0, hi1, lo1, hi2, lo2, hi3, lo3;
                        split2(W[(k0 + 0) * 64 + m], W[(k0 + 1) * 64 + m], hi0, lo0);
                        split2(W[(k0 + 2) * 64 + m], W[(k0 + 3) * 64 + m], hi1, lo1);
                        split2(W[(k0 + 4) * 64 + m], W[(k0 + 5) * 64 + m], hi2, lo2);
                        split2(W[(k0 + 6) * 64 + m], W[(k0 + 7) * 64 + m], hi3, lo3);
                        out[((ft * 2 + kt) * 2 + 0) * 64 + lane] = make_uint4(hi0, hi1, hi2, hi3);
                        out[((ft * 2 + kt) * 2 + 1) * 64 + lane] = make_uint4(lo0, lo1, lo2, lo3);
                    }
                }
            }
        }
        return;
    }
    int base = blockIdx.x * TILE;
    for (int i = threadIdx.x; i < NBUK; i += blockDim.x) {
        hist[i] = 0;
        lofs[i] = 0;
    }
    __syncthreads();
    int r[8];
    int c[8];
    int bk[8];
#pragma unroll
    for (int j = 0; j < 8; ++j) {
        int i = base + j * 256 + threadIdx.x;
        if (i < e) {
            r[j] = rows[i];
            c[j] = cols[i];
            bk[j] = r[j] >> RPB_LOG;
            atomicAdd(&hist[bk[j]], 1);
        } else {
            bk[j] = -1;
        }
    }
    __syncthreads();
    for (int b = threadIdx.x; b < NBUK; b += blockDim.x) {
        int h = hist[b];
        gbase[b] = h ? atomicAdd(&bcount[b], h) : 0;
    }
    __syncthreads();
#pragma unroll
    for (int j = 0; j < 8; ++j) {
        if (bk[j] >= 0) {
            int l = gbase[bk[j]] + atomicAdd(&lofs[bk[j]], 1);
            if (l < CAP) {
                unsigned int v = ((unsigned int)(r[j] & (RPB - 1)) << 17) | (unsigned int)c[j];
                binned[(size_t)bk[j] * CAP + l] = v;
            }
        }
    }
}

// Phase B: per-bucket counting sort + per-row deg/rowstart/dis production.
// Bucket base (exclusive scan of bcount over buckets < b) computed in-block.
__global__ void bucket_sort_k(const unsigned int* __restrict__ binned,
                              const int* __restrict__ bcount,
                              int* __restrict__ scols, int* __restrict__ rowstart,
                              int* __restrict__ deg, float* __restrict__ dis) {
    __shared__ int lcur[RPB];
    __shared__ int srs[RPB];
    __shared__ int wsum[8];
    __shared__ int redpart[8];
    __shared__ int sbase;
    int b = blockIdx.x;
    int row0 = b << RPB_LOG;
    int nrows = min(RPB, NN - row0);
    int cnt = bcount[b];
    const unsigned int* src = binned + (size_t)b * CAP;
    int tid = threadIdx.x;
    int lane = tid & 63;
    int wid = tid >> 6;

    // in-block exclusive bucket base: sum of bcount[i] for i < b
    int bv = (tid < NBUK && tid < b) ? bcount[tid] : 0;
    int bs = bv;
#pragma unroll
    for (int off = 1; off < 64; off <<= 1) {
        bs += __shfl_xor(bs, off, 64);
    }
    if (lane == 0) redpart[wid] = bs;
    __syncthreads();
    if (tid == 0) {
        int t = 0;
        for (int w = 0; w < 8; ++w) t += redpart[w];
        sbase = t;
    }
    if (tid < RPB) {
        lcur[tid] = 0;
    }
    __syncthreads();
    int bb = sbase;

    for (int i = tid; i < cnt; i += blockDim.x) {
        atomicAdd(&lcur[src[i] >> 17], 1);
    }
    __syncthreads();
    int d = (tid < nrows) ? lcur[tid] : 0;
    int inc = d;
#pragma unroll
    for (int off = 1; off < 64; off <<= 1) {
        int t = __shfl_up(inc, off);
        if (lane >= off) inc += t;
    }
    if (lane == 63) wsum[wid] = inc;
    __syncthreads();
    int wpre = 0;
    for (int w = 0; w < wid; ++w) wpre += wsum[w];
    int gstart = bb + wpre + inc - d;   // global exclusive prefix
    if (tid < nrows) {
        rowstart[row0 + tid] = gstart;
        deg[row0 + tid] = d;
        dis[row0 + tid] = rsqrtf((float)(d + 1));  // +1 self-loop
    }
    __syncthreads();
    if (tid < RPB) {
        srs[tid] = gstart;
        lcur[tid] = 0;
    }
    __syncthreads();
    for (int i = tid; i < cnt; i += blockDim.x) {
        unsigned int v = src[i];
        int rl = (int)(v >> 17);
        int pos = srs[rl] + atomicAdd(&lcur[rl], 1);
        scols[pos] = (int)(v & 0x1FFFFu);
    }
}

// MFMA GEMM: D = W^T · X^T via mfma_f32_16x16x32_bf16 with bf16 hi/lo split
// (hi*hi + hi*lo + lo*hi => ~fp32 accuracy). One wave per 16-row tile.
// C/D layout: col=lane&15 -> row, row=(lane>>4)*4+reg -> feature => each lane
// holds 4 consecutive features -> 8B packed-fp16 stores.
//   mode 1 (layer 1): per output row c computes BOTH products:
//     P[c] = dis[c]*(x[c]@W),  N[c] = dis[c]*(x[perm[c]]@W)  (input-side
//     gather of x[perm[c]], fully DENSE 256B row writes -> no scatter/RFO).
//   mode 2 (layer 2): rows < nmod are P (off 0), rows >= nmod are N (off 64),
//     both scaled by dis[rm]; single product.
__global__ void gemm64_mfma_k(const float* __restrict__ in, const uint4* __restrict__ wf,
                              ushort_t* __restrict__ tPN, const int* __restrict__ perm,
                              const float* __restrict__ dis, int n, int nmod, int mode) {
    int lane  = threadIdx.x & 63;
    int wtile = (int)((blockIdx.x * blockDim.x + threadIdx.x) >> 6);
    if (wtile * 16 >= n) return;
    int node = wtile * 16 + (lane & 15);
    int kg   = lane >> 4;  // 0..3

    FragU whi[4][2];
    FragU wlo[4][2];
#pragma unroll
    for (int ft = 0; ft < 4; ++ft) {
#pragma unroll
        for (int kt = 0; kt < 2; ++kt) {
            whi[ft][kt].v = wf[((ft * 2 + kt) * 2 + 0) * 64 + lane];
            wlo[ft][kt].v = wf[((ft * 2 + kt) * 2 + 1) * 64 + lane];
        }
    }

    const float4* xr = (const float4*)in;
    size_t rbase = (size_t)node * 16 + (size_t)(kg * 2);

    if (mode == 1) {
        int pnode = perm[node];
        size_t pbase = (size_t)pnode * 16 + (size_t)(kg * 2);
        f32x4 accP[4];
        f32x4 accN[4];
#pragma unroll
        for (int ft = 0; ft < 4; ++ft) {
            accP[ft] = f32x4{0.f, 0.f, 0.f, 0.f};
            accN[ft] = f32x4{0.f, 0.f, 0.f, 0.f};
        }
#pragma unroll
        for (int kt = 0; kt < 2; ++kt) {
            float4 a0 = xr[rbase + kt * 8];
            float4 a1 = xr[rbase + kt * 8 + 1];
            float4 g0 = xr[pbase + kt * 8];
            float4 g1 = xr[pbase + kt * 8 + 1];
            unsigned int h0, l0, h1, l1, h2, l2, h3, l3;
            split2(a0.x, a0.y, h0, l0);
            split2(a0.z, a0.w, h1, l1);
            split2(a1.x, a1.y, h2, l2);
            split2(a1.z, a1.w, h3, l3);
            FragU xhiP, xloP;
            xhiP.v = make_uint4(h0, h1, h2, h3);
            xloP.v = make_uint4(l0, l1, l2, l3);
            split2(g0.x, g0.y, h0, l0);
            split2(g0.z, g0.w, h1, l1);
            split2(g1.x, g1.y, h2, l2);
            split2(g1.z, g1.w, h3, l3);
            FragU xhiN, xloN;
            xhiN.v = make_uint4(h0, h1, h2, h3);
            xloN.v = make_uint4(l0, l1, l2, l3);
#pragma unroll
            for (int ft = 0; ft < 4; ++ft) {
                accP[ft] = __builtin_amdgcn_mfma_f32_16x16x32_bf16(whi[ft][kt].s, xhiP.s, accP[ft], 0, 0, 0);
                accP[ft] = __builtin_amdgcn_mfma_f32_16x16x32_bf16(whi[ft][kt].s, xloP.s, accP[ft], 0, 0, 0);
                accP[ft] = __builtin_amdgcn_mfma_f32_16x16x32_bf16(wlo[ft][kt].s, xhiP.s, accP[ft], 0, 0, 0);
                accN[ft] = __builtin_amdgcn_mfma_f32_16x16x32_bf16(whi[ft][kt].s, xhiN.s, accN[ft], 0, 0, 0);
                accN[ft] = __builtin_amdgcn_mfma_f32_16x16x32_bf16(whi[ft][kt].s, xloN.s, accN[ft], 0, 0, 0);
                accN[ft] = __builtin_amdgcn_mfma_f32_16x16x32_bf16(wlo[ft][kt].s, xhiN.s, accN[ft], 0, 0, 0);
            }
        }
        int fo = kg * 4;
        float s = dis[node];
        ushort_t* p = tPN + (size_t)node * 128;
#pragma unroll
        for (int ft = 0; ft < 4; ++ft) {
            uint2 up = make_uint2(packh(s * accP[ft][0], s * accP[ft][1]),
                                  packh(s * accP[ft][2], s * accP[ft][3]));
            *(uint2*)(p + ft * 16 + fo) = up;
            uint2 un = make_uint2(packh(s * accN[ft][0], s * accN[ft][1]),
                                  packh(s * accN[ft][2], s * accN[ft][3]));
            *(uint2*)(p + 64 + ft * 16 + fo) = un;
        }
    } else {
        f32x4 acc[4];
#pragma unroll
        for (int ft = 0; ft < 4; ++ft) {
            acc[ft] = f32x4{0.f, 0.f, 0.f, 0.f};
        }
#pragma unroll
        for (int kt = 0; kt < 2; ++kt) {
            float4 a0 = xr[rbase + kt * 8];
            float4 a1 = xr[rbase + kt * 8 + 1];
            unsigned int h0, l0, h1, l1, h2, l2, h3, l3;
            split2(a0.x, a0.y, h0, l0);
            split2(a0.z, a0.w, h1, l1);
            split2(a1.x, a1.y, h2, l2);
            split2(a1.z, a1.w, h3, l3);
            FragU xhi, xlo;
            xhi.v = make_uint4(h0, h1, h2, h3);
            xlo.v = make_uint4(l0, l1, l2, l3);
#pragma unroll
            for (int ft = 0; ft < 4; ++ft) {
                acc[ft] = __builtin_amdgcn_mfma_f32_16x16x32_bf16(whi[ft][kt].s, xhi.s, acc[ft], 0, 0, 0);
                acc[ft] = __builtin_amdgcn_mfma_f32_16x16x32_bf16(whi[ft][kt].s, xlo.s, acc[ft], 0, 0, 0);
                acc[ft] = __builtin_amdgcn_mfma_f32_16x16x32_bf16(wlo[ft][kt].s, xhi.s, acc[ft], 0, 0, 0);
            }
        }
        int fo = kg * 4;
        int rm  = (node >= nmod) ? node - nmod : node;
        int off = (node >= nmod) ? 64 : 0;
        float s = dis[rm];
        ushort_t* p = tPN + (size_t)rm * 128 + off;
#pragma unroll
        for (int ft = 0; ft < 4; ++ft) {
            uint2 u = make_uint2(packh(s * acc[ft][0], s * acc[ft][1]),
                                 packh(s * acc[ft][2], s * acc[ft][3]));
            *(uint2*)(p + ft * 16 + fo) = u;
        }
    }
}

// Dual gather-aggregate over the interleaved fp16 table. One wave per row;
// lanes 0-31 = P half, 32-63 = N half; each lane covers 2 features via one 4B load.
// outX[r] = dis[r]*(sum_j tX[c_j] + tX[r]) + b  (+ optional PReLU)
// (exact Round-2 structure: uniform scalar scols reads, 4-deep unroll)
__global__ void agg_dual_k(const ushort_t* __restrict__ tPN,
                           float* __restrict__ dstP, float* __restrict__ dstN,
                           const float* __restrict__ dis,
                           const int* __restrict__ rowstart, const int* __restrict__ deg,
                           const int* __restrict__ scols,
                           const float* __restrict__ bias, const float* __restrict__ prelu_a,
                           int n) {
    int lane = threadIdx.x & 63;
    int hl = lane & 31;
    int half = lane >> 5;
    int r = blockIdx.x * (blockDim.x >> 6) + (threadIdx.x >> 6);
    if (r >= n) return;
    int rs   = __builtin_amdgcn_readfirstlane(r);
    int base = __builtin_amdgcn_readfirstlane(rowstart[rs]);
    int dg   = __builtin_amdgcn_readfirstlane(deg[rs]);
    float dr = dis[rs];
    size_t lofs = (size_t)(half * 64 + hl * 2);
    unsigned int sv = *(const unsigned int*)(tPN + (size_t)rs * 128 + lofs);
    float2 fs = h2f(sv);
    float a0 = fs.x;
    float a1 = fs.y;     // self-loop term
    int j = 0;
    for (; j + 4 <= dg; j += 4) {
        int c0 = scols[base + j];
        int c1 = scols[base + j + 1];
        int c2 = scols[base + j + 2];
        int c3 = scols[base + j + 3];
        unsigned int v0 = *(const unsigned int*)(tPN + (size_t)c0 * 128 + lofs);
        unsigned int v1 = *(const unsigned int*)(tPN + (size_t)c1 * 128 + lofs);
        unsigned int v2 = *(const unsigned int*)(tPN + (size_t)c2 * 128 + lofs);
        unsigned int v3 = *(const unsigned int*)(tPN + (size_t)c3 * 128 + lofs);
        float2 f0 = h2f(v0);
        float2 f1 = h2f(v1);
        float2 f2 = h2f(v2);
        float2 f3 = h2f(v3);
        a0 += f0.x + f1.x + f2.x + f3.x;
        a1 += f0.y + f1.y + f2.y + f3.y;
    }
    for (; j < dg; ++j) {
        int c = scols[base + j];
        unsigned int v = *(const unsigned int*)(tPN + (size_t)c * 128 + lofs);
        float2 f = h2f(v);
        a0 += f.x;
        a1 += f.y;
    }
    float2 bv = *(const float2*)(bias + 2 * hl);
    float v0 = fmaf(dr, a0, bv.x);
    float v1 = fmaf(dr, a1, bv.y);
    if (prelu_a) {
        float a = *prelu_a;
        v0 = v0 >= 0.f ? v0 : a * v0;
        v1 = v1 >= 0.f ? v1 : a * v1;
    }
    float* dst = half ? dstN : dstP;
    *(float2*)(dst + (size_t)rs * D + 2 * hl) = float2{v0, v1};
}

// atomic-free summary: per-wave partial sums into part[wave][64]
__global__ void summary_partial_k(const float* __restrict__ pos, float* __restrict__ part, int n) {
    int lane = threadIdx.x & 63;
    int wave = (blockIdx.x * blockDim.x + threadIdx.x) >> 6;
    int nw = (gridDim.x * blockDim.x) >> 6;
    float s = 0.f;
    for (int r = wave; r < n; r += nw) {
        s += pos[(size_t)r * D + lane];
    }
    part[(size_t)wave * D + lane] = s;
}

__global__ void summary_final_k(const float* __restrict__ part, float* __restrict__ out, int n) {
    int f = threadIdx.x;
    if (f < D) {
        float s = 0.f;
        for (int w = 0; w < SUMW; ++w) {
            s += part[(size_t)w * D + f];
        }
        float m = s / (float)n;
        out[f] = 1.f / (1.f + expf(-m));
    }
}

} // namespace

extern "C" void kernel_launch(void* const* d_in, const int* in_sizes, int n_in,
                              void* d_out, int out_size, void* d_ws, size_t ws_size,
                              hipStream_t stream) {
    (void)in_sizes; (void)n_in; (void)out_size; (void)ws_size;
    const float* x       = (const float*)d_in[0];
    const int*   ei      = (const int*)  d_in[1];
    const int*   perm    = (const int*)  d_in[2];
    const float* W1      = (const float*)d_in[3];
    const float* b1      = (const float*)d_in[4];
    const float* prelu_a = (const float*)d_in[5];
    const float* W2      = (const float*)d_in[6];
    const float* b2      = (const float*)d_in[7];

    float* outP = (float*)d_out;
    float* outN = outP + (size_t)NN * D;
    float* outS = outN + (size_t)NN * D;

    const int* erows = ei;
    const int* ecols = ei + NE;

    char* ws = (char*)d_ws;
    size_t off = 0;
    auto alloc = [&](size_t bytes) {
        void* p = ws + off;
        off = (off + bytes + 255) & ~(size_t)255;
        return p;
    };
    int*      deg      = (int*)     alloc((size_t)NN * 4);
    float*    dis      = (float*)   alloc((size_t)NN * 4);
    int*      rowstart = (int*)     alloc((size_t)NN * 4);
    int*      bcount   = (int*)     alloc((size_t)NBUK * 4);
    unsigned int* binned = (unsigned int*)alloc((size_t)NBUK * CAP * 4);  // 6.4 MB
    int*      scols    = (int*)     alloc((size_t)NE * 4);
    ushort_t* tPN      = (ushort_t*)alloc((size_t)NN * 128 * 2);   // interleaved dual table (fp16), 25.6 MB
    float*    aggPN    = (float*)   alloc((size_t)2 * NN * D * 4); // [aggP | aggN], 51.2 MB
    float*    aggP     = aggPN;
    float*    aggN     = aggPN + (size_t)NN * D;
    float*    part     = (float*)   alloc((size_t)SUMW * D * 4);   // 256 KB
    uint4*    wfrag    = (uint4*)   alloc((size_t)2 * 1024 * 16);  // W1|W2 bf16 hi/lo frags, 32 KB
    // ~90 MB total

    hipMemsetAsync(bcount, 0, (size_t)NBUK * 4, stream);

    // preprocessing: fused bin+wfrag -> per-bucket sort (scan in-block)
    binw_k<<<NTILES + 1, 256, 0, stream>>>(erows, ecols, bcount, binned, NE, W1, W2, wfrag);
    bucket_sort_k<<<NBUK, 512, 0, stream>>>(binned, bcount, scols, rowstart, deg, dis);

    const int aggBlocks = (NN + 3) / 4;

    // layer 1: tPN[c] = [dis[c]*(x[c]@W1) | dis[c]*(x[perm[c]]@W1)]  (dense writes)
    gemm64_mfma_k<<<(NN / 16 + 3) / 4, 256, 0, stream>>>(x, wfrag, tPN, perm, dis, NN, NN, 1);
    agg_dual_k<<<aggBlocks, 256, 0, stream>>>(tPN, aggP, aggN, dis, rowstart, deg,
                                              scols, b1, prelu_a, NN);

    // layer 2: one MFMA gemm over [aggP|aggN] (200k rows) -> interleaved scaled table
    gemm64_mfma_k<<<(2 * NN / 16 + 3) / 4, 256, 0, stream>>>(aggPN, wfrag + 1024, tPN, nullptr,
                                                             dis, 2 * NN, NN, 2);
    agg_dual_k<<<aggBlocks, 256, 0, stream>>>(tPN, outP, outN, dis, rowstart, deg,
                                              scols, b2, nullptr, NN);

    // summary = sigmoid(mean(positive, axis=0))
    summary_partial_k<<<256, 256, 0, stream>>>(outP, part, NN);
    summary_final_k<<<1, 64, 0, stream>>>(part, outS, NN);
}

// Round 6
// 284.718 us; speedup vs baseline: 1.2828x; 1.0559x over previous
//
#include <hip/hip_runtime.h>
#include <hip/hip_fp16.h>
#include <math.h>

namespace {

constexpr int NN = 100000;   // nodes
constexpr int NE = 1000000;  // edges
constexpr int D  = 64;       // feature dim

constexpr int RPB_LOG = 8;                        // rows per bucket = 256
constexpr int RPB = 1 << RPB_LOG;
constexpr int NBUK = (NN + RPB - 1) >> RPB_LOG;   // 391 buckets
constexpr int CAP = 4096;                         // bucket capacity (mean 2558, +30 sigma)
constexpr int TILE = 2048;                        // edges per bin tile
constexpr int NTILES = (NE + TILE - 1) / TILE;    // 489
constexpr int SUMW = 1024;                        // summary partial waves

using ushort_t = unsigned short;
typedef __attribute__((ext_vector_type(8))) short short8;  // 8 bf16 (4 VGPRs)
typedef __attribute__((ext_vector_type(4))) float f32x4;   // MFMA 16x16 accumulator

union FragU { uint4 v; short8 s; };

// split two fp32 into packed bf16 hi parts and packed bf16 lo (residual) parts.
__device__ inline void split2(float f0, float f1, unsigned int& hi, unsigned int& lo) {
    unsigned int u0 = __float_as_uint(f0);
    unsigned int u1 = __float_as_uint(f1);
    hi = (u0 >> 16) | (u1 & 0xffff0000u);
    float l0 = f0 - __uint_as_float(u0 & 0xffff0000u);
    float l1 = f1 - __uint_as_float(u1 & 0xffff0000u);
    lo = (__float_as_uint(l0) >> 16) | (__float_as_uint(l1) & 0xffff0000u);
}

__device__ inline unsigned int packh(float a, float b) {   // 2x fp16 (RNE) packed
    union { __half2 h; unsigned int u; } cv;
    cv.h = __float22half2_rn(make_float2(a, b));
    return cv.u;
}

__device__ inline float2 h2f(unsigned int v) {
    union { unsigned int u; __half2 h; } cv;
    cv.u = v;
    return __half22float2(cv.h);
}

// Fused Phase A + weight-fragment precompute.
// Blocks [0, NTILES): bin edges into 391 fixed-capacity row-range buckets.
//   Payload packed: (r & 255) << 17 | c   (c < 2^17)
// Block NTILES: build MFMA A-operand fragments for W1|W2 (bf16 hi/lo),
//   layout per matrix: [ftile(4)][ktile(2)][hi/lo(2)][lane(64)] x 16B;
//   lane l holds A[m][k], m = ft*16 + (l&15), k = kt*32 + (l>>4)*8 + j.
__global__ void binw_k(const int* __restrict__ rows, const int* __restrict__ cols,
                       int* __restrict__ bcount, unsigned int* __restrict__ binned, int e,
                       const float* __restrict__ W1, const float* __restrict__ W2,
                       uint4* __restrict__ fb) {
    __shared__ int hist[NBUK];
    __shared__ int gbase[NBUK];
    __shared__ int lofs[NBUK];
    if (blockIdx.x == NTILES) {
        int lane = threadIdx.x;
        if (lane < 64) {
            for (int w = 0; w < 2; ++w) {
                const float* W = (w != 0) ? W2 : W1;
                uint4* out = fb + w * 1024;
                for (int ft = 0; ft < 4; ++ft) {
                    for (int kt = 0; kt < 2; ++kt) {
                        int m  = ft * 16 + (lane & 15);
                        int k0 = kt * 32 + (lane >> 4) * 8;
                        unsigned int hi0, lo0, hi1, lo1, hi2, lo2, hi3, lo3;
                        split2(W[(k0 + 0) * 64 + m], W[(k0 + 1) * 64 + m], hi0, lo0);
                        split2(W[(k0 + 2) * 64 + m], W[(k0 + 3) * 64 + m], hi1, lo1);
                        split2(W[(k0 + 4) * 64 + m], W[(k0 + 5) * 64 + m], hi2, lo2);
                        split2(W[(k0 + 6) * 64 + m], W[(k0 + 7) * 64 + m], hi3, lo3);
                        out[((ft * 2 + kt) * 2 + 0) * 64 + lane] = make_uint4(hi0, hi1, hi2, hi3);
                        out[((ft * 2 + kt) * 2 + 1) * 64 + lane] = make_uint4(lo0, lo1, lo2, lo3);
                    }
                }
            }
        }
        return;
    }
    int base = blockIdx.x * TILE;
    for (int i = threadIdx.x; i < NBUK; i += blockDim.x) {
        hist[i] = 0;
        lofs[i] = 0;
    }
    __syncthreads();
    int r[8];
    int c[8];
    int bk[8];
#pragma unroll
    for (int j = 0; j < 8; ++j) {
        int i = base + j * 256 + threadIdx.x;
        if (i < e) {
            r[j] = rows[i];
            c[j] = cols[i];
            bk[j] = r[j] >> RPB_LOG;
            atomicAdd(&hist[bk[j]], 1);
        } else {
            bk[j] = -1;
        }
    }
    __syncthreads();
    for (int b = threadIdx.x; b < NBUK; b += blockDim.x) {
        int h = hist[b];
        gbase[b] = h ? atomicAdd(&bcount[b], h) : 0;
    }
    __syncthreads();
#pragma unroll
    for (int j = 0; j < 8; ++j) {
        if (bk[j] >= 0) {
            int l = gbase[bk[j]] + atomicAdd(&lofs[bk[j]], 1);
            if (l < CAP) {
                unsigned int v = ((unsigned int)(r[j] & (RPB - 1)) << 17) | (unsigned int)c[j];
                binned[(size_t)bk[j] * CAP + l] = v;
            }
        }
    }
}

// Phase B: per-bucket counting sort + per-row deg/rowstart/dis production.
// Bucket base (exclusive scan of bcount over buckets < b) computed in-block.
__global__ void bucket_sort_k(const unsigned int* __restrict__ binned,
                              const int* __restrict__ bcount,
                              int* __restrict__ scols, int* __restrict__ rowstart,
                              int* __restrict__ deg, float* __restrict__ dis) {
    __shared__ int lcur[RPB];
    __shared__ int srs[RPB];
    __shared__ int wsum[8];
    __shared__ int redpart[8];
    __shared__ int sbase;
    int b = blockIdx.x;
    int row0 = b << RPB_LOG;
    int nrows = min(RPB, NN - row0);
    int cnt = bcount[b];
    const unsigned int* src = binned + (size_t)b * CAP;
    int tid = threadIdx.x;
    int lane = tid & 63;
    int wid = tid >> 6;

    // in-block exclusive bucket base: sum of bcount[i] for i < b
    int bv = (tid < NBUK && tid < b) ? bcount[tid] : 0;
    int bs = bv;
#pragma unroll
    for (int off = 1; off < 64; off <<= 1) {
        bs += __shfl_xor(bs, off, 64);
    }
    if (lane == 0) redpart[wid] = bs;
    __syncthreads();
    if (tid == 0) {
        int t = 0;
        for (int w = 0; w < 8; ++w) t += redpart[w];
        sbase = t;
    }
    if (tid < RPB) {
        lcur[tid] = 0;
    }
    __syncthreads();
    int bb = sbase;

    for (int i = tid; i < cnt; i += blockDim.x) {
        atomicAdd(&lcur[src[i] >> 17], 1);
    }
    __syncthreads();
    int d = (tid < nrows) ? lcur[tid] : 0;
    int inc = d;
#pragma unroll
    for (int off = 1; off < 64; off <<= 1) {
        int t = __shfl_up(inc, off);
        if (lane >= off) inc += t;
    }
    if (lane == 63) wsum[wid] = inc;
    __syncthreads();
    int wpre = 0;
    for (int w = 0; w < wid; ++w) wpre += wsum[w];
    int gstart = bb + wpre + inc - d;   // global exclusive prefix
    if (tid < nrows) {
        rowstart[row0 + tid] = gstart;
        deg[row0 + tid] = d;
        dis[row0 + tid] = rsqrtf((float)(d + 1));  // +1 self-loop
    }
    __syncthreads();
    if (tid < RPB) {
        srs[tid] = gstart;
        lcur[tid] = 0;
    }
    __syncthreads();
    for (int i = tid; i < cnt; i += blockDim.x) {
        unsigned int v = src[i];
        int rl = (int)(v >> 17);
        int pos = srs[rl] + atomicAdd(&lcur[rl], 1);
        scols[pos] = (int)(v & 0x1FFFFu);
    }
}

// Layer-1 MFMA GEMM: per output row c computes BOTH products
//   P[c] = dis[c]*(x[c]@W1),  N[c] = dis[c]*(x[perm[c]]@W1)
// via mfma_f32_16x16x32_bf16 with bf16 hi/lo split (~fp32 accuracy).
// One wave per 16-row tile; dense 256B interleaved-row writes (no scatter).
__global__ void gemm1_k(const float* __restrict__ in, const uint4* __restrict__ wf,
                        ushort_t* __restrict__ tPN, const int* __restrict__ perm,
                        const float* __restrict__ dis, int n) {
    int lane  = threadIdx.x & 63;
    int wtile = (int)((blockIdx.x * blockDim.x + threadIdx.x) >> 6);
    if (wtile * 16 >= n) return;
    int node = wtile * 16 + (lane & 15);
    int kg   = lane >> 4;  // 0..3

    FragU whi[4][2];
    FragU wlo[4][2];
#pragma unroll
    for (int ft = 0; ft < 4; ++ft) {
#pragma unroll
        for (int kt = 0; kt < 2; ++kt) {
            whi[ft][kt].v = wf[((ft * 2 + kt) * 2 + 0) * 64 + lane];
            wlo[ft][kt].v = wf[((ft * 2 + kt) * 2 + 1) * 64 + lane];
        }
    }

    const float4* xr = (const float4*)in;
    size_t rbase = (size_t)node * 16 + (size_t)(kg * 2);
    int pnode = perm[node];
    size_t pbase = (size_t)pnode * 16 + (size_t)(kg * 2);
    f32x4 accP[4];
    f32x4 accN[4];
#pragma unroll
    for (int ft = 0; ft < 4; ++ft) {
        accP[ft] = f32x4{0.f, 0.f, 0.f, 0.f};
        accN[ft] = f32x4{0.f, 0.f, 0.f, 0.f};
    }
#pragma unroll
    for (int kt = 0; kt < 2; ++kt) {
        float4 a0 = xr[rbase + kt * 8];
        float4 a1 = xr[rbase + kt * 8 + 1];
        float4 g0 = xr[pbase + kt * 8];
        float4 g1 = xr[pbase + kt * 8 + 1];
        unsigned int h0, l0, h1, l1, h2, l2, h3, l3;
        split2(a0.x, a0.y, h0, l0);
        split2(a0.z, a0.w, h1, l1);
        split2(a1.x, a1.y, h2, l2);
        split2(a1.z, a1.w, h3, l3);
        FragU xhiP, xloP;
        xhiP.v = make_uint4(h0, h1, h2, h3);
        xloP.v = make_uint4(l0, l1, l2, l3);
        split2(g0.x, g0.y, h0, l0);
        split2(g0.z, g0.w, h1, l1);
        split2(g1.x, g1.y, h2, l2);
        split2(g1.z, g1.w, h3, l3);
        FragU xhiN, xloN;
        xhiN.v = make_uint4(h0, h1, h2, h3);
        xloN.v = make_uint4(l0, l1, l2, l3);
#pragma unroll
        for (int ft = 0; ft < 4; ++ft) {
            accP[ft] = __builtin_amdgcn_mfma_f32_16x16x32_bf16(whi[ft][kt].s, xhiP.s, accP[ft], 0, 0, 0);
            accP[ft] = __builtin_amdgcn_mfma_f32_16x16x32_bf16(whi[ft][kt].s, xloP.s, accP[ft], 0, 0, 0);
            accP[ft] = __builtin_amdgcn_mfma_f32_16x16x32_bf16(wlo[ft][kt].s, xhiP.s, accP[ft], 0, 0, 0);
            accN[ft] = __builtin_amdgcn_mfma_f32_16x16x32_bf16(whi[ft][kt].s, xhiN.s, accN[ft], 0, 0, 0);
            accN[ft] = __builtin_amdgcn_mfma_f32_16x16x32_bf16(whi[ft][kt].s, xloN.s, accN[ft], 0, 0, 0);
            accN[ft] = __builtin_amdgcn_mfma_f32_16x16x32_bf16(wlo[ft][kt].s, xhiN.s, accN[ft], 0, 0, 0);
        }
    }
    int fo = kg * 4;
    float s = dis[node];
    ushort_t* p = tPN + (size_t)node * 128;
#pragma unroll
    for (int ft = 0; ft < 4; ++ft) {
        uint2 up = make_uint2(packh(s * accP[ft][0], s * accP[ft][1]),
                              packh(s * accP[ft][2], s * accP[ft][3]));
        *(uint2*)(p + ft * 16 + fo) = up;
        uint2 un = make_uint2(packh(s * accN[ft][0], s * accN[ft][1]),
                              packh(s * accN[ft][2], s * accN[ft][3]));
        *(uint2*)(p + 64 + ft * 16 + fo) = un;
    }
}

// FUSED layer-1 aggregate + layer-2 GEMM. One block (4 waves) owns 16 rows.
// Phase 1 (gather, R2-proven structure): each wave aggregates 4 rows
// sequentially; lanes 0-31 = P half, 32-63 = N half, 2 feats/lane/4B-load;
// scols reads wave-uniform (scalar). H row (post bias+PReLU) parked in LDS
// [half][16][68] fp32 (pad 68 -> only free 2-way bank conflicts).
// Phase 2 (MFMA): waves 0,1 -> P tile, waves 2,3 -> N tile; 2 ftiles/wave;
// identical split2 hi/lo math as the old gemm2 (bit-identical numerics);
// epilogue scales by dis[row] and writes fp16 table tOut (dense 8B stores).
// Eliminates the 51.2MB aggPN round-trip and the gemm2 dispatch.
__global__ void agg_gemm_k(const ushort_t* __restrict__ tIn, ushort_t* __restrict__ tOut,
                           const float* __restrict__ dis,
                           const int* __restrict__ rowstart, const int* __restrict__ deg,
                           const int* __restrict__ scols,
                           const float* __restrict__ bias, const float* __restrict__ prelu_a,
                           const uint4* __restrict__ wf) {
    __shared__ float Hs[2][16][68];
    int tid = threadIdx.x;
    int lane = tid & 63;
    int wv = tid >> 6;                 // 0..3
    int row0 = blockIdx.x * 16;
    int hl = lane & 31;
    int half = lane >> 5;
    size_t lofs = (size_t)(half * 64 + hl * 2);
    float aPr = *prelu_a;

    for (int rr = 0; rr < 4; ++rr) {
        int r = row0 + wv * 4 + rr;
        int rs   = __builtin_amdgcn_readfirstlane(r);
        int base = __builtin_amdgcn_readfirstlane(rowstart[rs]);
        int dg   = __builtin_amdgcn_readfirstlane(deg[rs]);
        float dr = dis[rs];
        unsigned int sv = *(const unsigned int*)(tIn + (size_t)rs * 128 + lofs);
        float2 fs = h2f(sv);
        float a0 = fs.x;
        float a1 = fs.y;     // self-loop term
        int j = 0;
        for (; j + 4 <= dg; j += 4) {
            int c0 = scols[base + j];
            int c1 = scols[base + j + 1];
            int c2 = scols[base + j + 2];
            int c3 = scols[base + j + 3];
            unsigned int v0 = *(const unsigned int*)(tIn + (size_t)c0 * 128 + lofs);
            unsigned int v1 = *(const unsigned int*)(tIn + (size_t)c1 * 128 + lofs);
            unsigned int v2 = *(const unsigned int*)(tIn + (size_t)c2 * 128 + lofs);
            unsigned int v3 = *(const unsigned int*)(tIn + (size_t)c3 * 128 + lofs);
            float2 f0 = h2f(v0);
            float2 f1 = h2f(v1);
            float2 f2 = h2f(v2);
            float2 f3 = h2f(v3);
            a0 += f0.x + f1.x + f2.x + f3.x;
            a1 += f0.y + f1.y + f2.y + f3.y;
        }
        for (; j < dg; ++j) {
            int c = scols[base + j];
            unsigned int v = *(const unsigned int*)(tIn + (size_t)c * 128 + lofs);
            float2 f = h2f(v);
            a0 += f.x;
            a1 += f.y;
        }
        float2 bv = *(const float2*)(bias + 2 * hl);
        float v0 = fmaf(dr, a0, bv.x);
        float v1 = fmaf(dr, a1, bv.y);
        v0 = v0 >= 0.f ? v0 : aPr * v0;
        v1 = v1 >= 0.f ? v1 : aPr * v1;
        int rl = wv * 4 + rr;
        Hs[half][rl][2 * hl]     = v0;
        Hs[half][rl][2 * hl + 1] = v1;
    }
    __syncthreads();

    // layer-2: out[row] = dis[row] * (H[row] @ W2), per half
    int kg = lane >> 4;
    int nd = lane & 15;
    int hsel = wv >> 1;                // waves 0,1 -> P; 2,3 -> N
    int ftb = (wv & 1) * 2;            // ftiles {0,1} or {2,3}
    FragU whi[2][2];
    FragU wlo[2][2];
#pragma unroll
    for (int f2 = 0; f2 < 2; ++f2) {
#pragma unroll
        for (int kt = 0; kt < 2; ++kt) {
            whi[f2][kt].v = wf[(((ftb + f2) * 2 + kt) * 2 + 0) * 64 + lane];
            wlo[f2][kt].v = wf[(((ftb + f2) * 2 + kt) * 2 + 1) * 64 + lane];
        }
    }
    f32x4 acc[2];
    acc[0] = f32x4{0.f, 0.f, 0.f, 0.f};
    acc[1] = f32x4{0.f, 0.f, 0.f, 0.f};
#pragma unroll
    for (int kt = 0; kt < 2; ++kt) {
        float4 a0 = *(const float4*)&Hs[hsel][nd][kt * 32 + kg * 8];
        float4 a1 = *(const float4*)&Hs[hsel][nd][kt * 32 + kg * 8 + 4];
        unsigned int h0, l0, h1, l1, h2, l2, h3, l3;
        split2(a0.x, a0.y, h0, l0);
        split2(a0.z, a0.w, h1, l1);
        split2(a1.x, a1.y, h2, l2);
        split2(a1.z, a1.w, h3, l3);
        FragU xhi, xlo;
        xhi.v = make_uint4(h0, h1, h2, h3);
        xlo.v = make_uint4(l0, l1, l2, l3);
#pragma unroll
        for (int f2 = 0; f2 < 2; ++f2) {
            acc[f2] = __builtin_amdgcn_mfma_f32_16x16x32_bf16(whi[f2][kt].s, xhi.s, acc[f2], 0, 0, 0);
            acc[f2] = __builtin_amdgcn_mfma_f32_16x16x32_bf16(whi[f2][kt].s, xlo.s, acc[f2], 0, 0, 0);
            acc[f2] = __builtin_amdgcn_mfma_f32_16x16x32_bf16(wlo[f2][kt].s, xhi.s, acc[f2], 0, 0, 0);
        }
    }
    float s = dis[row0 + nd];
    ushort_t* p = tOut + (size_t)(row0 + nd) * 128 + hsel * 64;
    int fo = kg * 4;
#pragma unroll
    for (int f2 = 0; f2 < 2; ++f2) {
        uint2 u = make_uint2(packh(s * acc[f2][0], s * acc[f2][1]),
                             packh(s * acc[f2][2], s * acc[f2][3]));
        *(uint2*)(p + (ftb + f2) * 16 + fo) = u;
    }
}

// Dual gather-aggregate over the interleaved fp16 table (final layer).
// One wave per row; lanes 0-31 = P half, 32-63 = N half; 2 feats/lane.
// outX[r] = dis[r]*(sum_j tX[c_j] + tX[r]) + b
__global__ void agg_dual_k(const ushort_t* __restrict__ tPN,
                           float* __restrict__ dstP, float* __restrict__ dstN,
                           const float* __restrict__ dis,
                           const int* __restrict__ rowstart, const int* __restrict__ deg,
                           const int* __restrict__ scols,
                           const float* __restrict__ bias, int n) {
    int lane = threadIdx.x & 63;
    int hl = lane & 31;
    int half = lane >> 5;
    int r = blockIdx.x * (blockDim.x >> 6) + (threadIdx.x >> 6);
    if (r >= n) return;
    int rs   = __builtin_amdgcn_readfirstlane(r);
    int base = __builtin_amdgcn_readfirstlane(rowstart[rs]);
    int dg   = __builtin_amdgcn_readfirstlane(deg[rs]);
    float dr = dis[rs];
    size_t lofs = (size_t)(half * 64 + hl * 2);
    unsigned int sv = *(const unsigned int*)(tPN + (size_t)rs * 128 + lofs);
    float2 fs = h2f(sv);
    float a0 = fs.x;
    float a1 = fs.y;     // self-loop term
    int j = 0;
    for (; j + 4 <= dg; j += 4) {
        int c0 = scols[base + j];
        int c1 = scols[base + j + 1];
        int c2 = scols[base + j + 2];
        int c3 = scols[base + j + 3];
        unsigned int v0 = *(const unsigned int*)(tPN + (size_t)c0 * 128 + lofs);
        unsigned int v1 = *(const unsigned int*)(tPN + (size_t)c1 * 128 + lofs);
        unsigned int v2 = *(const unsigned int*)(tPN + (size_t)c2 * 128 + lofs);
        unsigned int v3 = *(const unsigned int*)(tPN + (size_t)c3 * 128 + lofs);
        float2 f0 = h2f(v0);
        float2 f1 = h2f(v1);
        float2 f2 = h2f(v2);
        float2 f3 = h2f(v3);
        a0 += f0.x + f1.x + f2.x + f3.x;
        a1 += f0.y + f1.y + f2.y + f3.y;
    }
    for (; j < dg; ++j) {
        int c = scols[base + j];
        unsigned int v = *(const unsigned int*)(tPN + (size_t)c * 128 + lofs);
        float2 f = h2f(v);
        a0 += f.x;
        a1 += f.y;
    }
    float2 bv = *(const float2*)(bias + 2 * hl);
    float v0 = fmaf(dr, a0, bv.x);
    float v1 = fmaf(dr, a1, bv.y);
    float* dst = half ? dstN : dstP;
    *(float2*)(dst + (size_t)rs * D + 2 * hl) = float2{v0, v1};
}

// atomic-free summary: per-wave partial sums into part[wave][64]
__global__ void summary_partial_k(const float* __restrict__ pos, float* __restrict__ part, int n) {
    int lane = threadIdx.x & 63;
    int wave = (blockIdx.x * blockDim.x + threadIdx.x) >> 6;
    int nw = (gridDim.x * blockDim.x) >> 6;
    float s = 0.f;
    for (int r = wave; r < n; r += nw) {
        s += pos[(size_t)r * D + lane];
    }
    part[(size_t)wave * D + lane] = s;
}

__global__ void summary_final_k(const float* __restrict__ part, float* __restrict__ out, int n) {
    int f = threadIdx.x;
    if (f < D) {
        float s = 0.f;
        for (int w = 0; w < SUMW; ++w) {
            s += part[(size_t)w * D + f];
        }
        float m = s / (float)n;
        out[f] = 1.f / (1.f + expf(-m));
    }
}

} // namespace

extern "C" void kernel_launch(void* const* d_in, const int* in_sizes, int n_in,
                              void* d_out, int out_size, void* d_ws, size_t ws_size,
                              hipStream_t stream) {
    (void)in_sizes; (void)n_in; (void)out_size; (void)ws_size;
    const float* x       = (const float*)d_in[0];
    const int*   ei      = (const int*)  d_in[1];
    const int*   perm    = (const int*)  d_in[2];
    const float* W1      = (const float*)d_in[3];
    const float* b1      = (const float*)d_in[4];
    const float* prelu_a = (const float*)d_in[5];
    const float* W2      = (const float*)d_in[6];
    const float* b2      = (const float*)d_in[7];

    float* outP = (float*)d_out;
    float* outN = outP + (size_t)NN * D;
    float* outS = outN + (size_t)NN * D;

    const int* erows = ei;
    const int* ecols = ei + NE;

    char* ws = (char*)d_ws;
    size_t off = 0;
    auto alloc = [&](size_t bytes) {
        void* p = ws + off;
        off = (off + bytes + 255) & ~(size_t)255;
        return p;
    };
    int*      deg      = (int*)     alloc((size_t)NN * 4);
    float*    dis      = (float*)   alloc((size_t)NN * 4);
    int*      rowstart = (int*)     alloc((size_t)NN * 4);
    int*      bcount   = (int*)     alloc((size_t)NBUK * 4);
    unsigned int* binned = (unsigned int*)alloc((size_t)NBUK * CAP * 4);  // 6.4 MB
    int*      scols    = (int*)     alloc((size_t)NE * 4);
    ushort_t* tPN      = (ushort_t*)alloc((size_t)NN * 128 * 2);   // layer-1 fp16 table, 25.6 MB
    ushort_t* tPN2     = (ushort_t*)alloc((size_t)NN * 128 * 2);   // layer-2 fp16 table, 25.6 MB
    float*    part     = (float*)   alloc((size_t)SUMW * D * 4);   // 256 KB
    uint4*    wfrag    = (uint4*)   alloc((size_t)2 * 1024 * 16);  // W1|W2 bf16 hi/lo frags, 32 KB
    // ~65 MB total

    hipMemsetAsync(bcount, 0, (size_t)NBUK * 4, stream);

    // preprocessing: fused bin+wfrag -> per-bucket sort (scan in-block)
    binw_k<<<NTILES + 1, 256, 0, stream>>>(erows, ecols, bcount, binned, NE, W1, W2, wfrag);
    bucket_sort_k<<<NBUK, 512, 0, stream>>>(binned, bcount, scols, rowstart, deg, dis);

    // layer 1 GEMM: tPN[c] = [dis[c]*(x[c]@W1) | dis[c]*(x[perm[c]]@W1)]
    gemm1_k<<<(NN / 16 + 3) / 4, 256, 0, stream>>>(x, wfrag, tPN, perm, dis, NN);

    // fused layer-1 aggregate (+b1,PReLU) + layer-2 GEMM -> scaled fp16 table
    agg_gemm_k<<<NN / 16, 256, 0, stream>>>(tPN, tPN2, dis, rowstart, deg, scols,
                                            b1, prelu_a, wfrag + 1024);

    // final aggregate (+b2) -> outputs
    agg_dual_k<<<(NN + 3) / 4, 256, 0, stream>>>(tPN2, outP, outN, dis, rowstart, deg,
                                                 scols, b2, NN);

    // summary = sigmoid(mean(positive, axis=0))
    summary_partial_k<<<256, 256, 0, stream>>>(outP, part, NN);
    summary_final_k<<<1, 64, 0, stream>>>(part, outS, NN);
}